// Round 1
// baseline (28.346 us; speedup 1.0000x reference)
//
#include <hip/hip_runtime.h>

// GMM 2D activation, fully learnable.
// x:(B,S,D) f32, means:(K,2), inv_var_covar:(K,2,2), weights:(1,1,D/2,K,2)
// out[b,s,2d+c] = x[b,s,2d+c] * sum_k exp(-0.5 * diff^T Sinv_k diff) * w[d,k,c]
// where diff = (x[b,s,2d], x[b,s,2d+1]) - means[k].
// B=4, S=2048, D=2048, K=4.

#define D2    1024   // D/2
#define KCOMP 4

__global__ __launch_bounds__(256) void gmm2d_kernel(
    const float4* __restrict__ x4,
    const float*  __restrict__ means,   // (K,2)
    const float*  __restrict__ icov,    // (K,2,2)
    const float4* __restrict__ w4,      // (D/2 * K * 2)/4 float4s, layout [d][k][c]
    float4*       __restrict__ out4,
    int n4)
{
    // Broadcast params -> registers (wave-uniform scalar loads).
    float m0[KCOMP], m1[KCOMP], ia[KCOMP], ib[KCOMP], ic[KCOMP], idd[KCOMP];
#pragma unroll
    for (int k = 0; k < KCOMP; ++k) {
        m0[k]  = means[k * 2 + 0];
        m1[k]  = means[k * 2 + 1];
        ia[k]  = icov[k * 4 + 0];
        ib[k]  = icov[k * 4 + 1];
        ic[k]  = icov[k * 4 + 2];
        idd[k] = icov[k * 4 + 3];
    }

    const int stride = gridDim.x * blockDim.x;
    for (int i = blockIdx.x * blockDim.x + threadIdx.x; i < n4; i += stride) {
        float4 xv = x4[i];
        // global pair index = i*2; pair index within row = mod D/2 (power of 2)
        const int dp = (i * 2) & (D2 - 1);
        // weights for pairs dp, dp+1: 16 consecutive floats at dp*8
        const float4 wa = w4[dp * 2 + 0];  // pair0: k0c0 k0c1 k1c0 k1c1
        const float4 wb = w4[dp * 2 + 1];  // pair0: k2c0 k2c1 k3c0 k3c1
        const float4 wc = w4[dp * 2 + 2];  // pair1: k0c0 k0c1 k1c0 k1c1
        const float4 wd = w4[dp * 2 + 3];  // pair1: k2c0 k2c1 k3c0 k3c1

        float p0[KCOMP], p1[KCOMP];
#pragma unroll
        for (int k = 0; k < KCOMP; ++k) {
            // pair 0: (xv.x, xv.y)
            float d0 = xv.x - m0[k];
            float d1 = xv.y - m1[k];
            float q  = d0 * (ia[k] * d0 + ib[k] * d1) + d1 * (ic[k] * d0 + idd[k] * d1);
            p0[k] = __expf(-0.5f * q);
            // pair 1: (xv.z, xv.w)
            float e0 = xv.z - m0[k];
            float e1 = xv.w - m1[k];
            float r  = e0 * (ia[k] * e0 + ib[k] * e1) + e1 * (ic[k] * e0 + idd[k] * e1);
            p1[k] = __expf(-0.5f * r);
        }

        float r00 = p0[0] * wa.x + p0[1] * wa.z + p0[2] * wb.x + p0[3] * wb.z;
        float r01 = p0[0] * wa.y + p0[1] * wa.w + p0[2] * wb.y + p0[3] * wb.w;
        float r10 = p1[0] * wc.x + p1[1] * wc.z + p1[2] * wd.x + p1[3] * wd.z;
        float r11 = p1[0] * wc.y + p1[1] * wc.w + p1[2] * wd.y + p1[3] * wd.w;

        float4 ov;
        ov.x = xv.x * r00;
        ov.y = xv.y * r01;
        ov.z = xv.z * r10;
        ov.w = xv.w * r11;
        out4[i] = ov;
    }
}

extern "C" void kernel_launch(void* const* d_in, const int* in_sizes, int n_in,
                              void* d_out, int out_size, void* d_ws, size_t ws_size,
                              hipStream_t stream) {
    const float4* x4    = (const float4*)d_in[0];
    const float*  means = (const float*)d_in[1];
    const float*  icov  = (const float*)d_in[2];
    const float4* w4    = (const float4*)d_in[3];
    float4*       out4  = (float4*)d_out;

    const int n4 = out_size / 4;              // 4*2048*2048/4 = 4194304
    const int block = 256;
    int grid = 2048;                          // grid-stride, ~8 iters/thread
    if (grid > (n4 + block - 1) / block) grid = (n4 + block - 1) / block;

    gmm2d_kernel<<<grid, block, 0, stream>>>(x4, means, icov, w4, out4, n4);
}

// Round 2
// 26.057 us; speedup vs baseline: 1.0879x; 1.0879x over previous
//
#include <hip/hip_runtime.h>

// GMM 2D activation, fully learnable.
// x:(B,S,D) f32, means:(K,2), inv_var_covar:(K,2,2), weights:(1,1,D/2,K,2)
// out[b,s,2d+c] = x[b,s,2d+c] * sum_k exp(-0.5*diff^T Sinv_k diff) * w[d,k,c]
// B=4, S=2048, D=2048, K=4.
//
// Layout strategy: each thread owns ONE fixed float4-column (2 GMM pairs),
// so its 16 weight floats load once; the row loop is a pure x-stream.

#define D2      1024          // D/2 pairs per row
#define ROW4    512           // float4s per row (D/4)
#define KCOMP   4
#define RPB     8             // rows per block
#define NROWS   8192          // B*S

__global__ __launch_bounds__(256) void gmm2d_kernel(
    const float4* __restrict__ x4,
    const float*  __restrict__ means,   // (K,2)
    const float*  __restrict__ icov,    // (K,2,2)
    const float4* __restrict__ w4,      // [d][k][c] as float4s
    float4*       __restrict__ out4)
{
    // Broadcast params -> registers (wave-uniform scalar loads).
    float m0[KCOMP], m1[KCOMP], ia[KCOMP], ib[KCOMP], ic[KCOMP], idd[KCOMP];
#pragma unroll
    for (int k = 0; k < KCOMP; ++k) {
        m0[k]  = means[k * 2 + 0];
        m1[k]  = means[k * 2 + 1];
        ia[k]  = icov[k * 4 + 0];
        ib[k]  = icov[k * 4 + 1];
        ic[k]  = icov[k * 4 + 2];
        idd[k] = icov[k * 4 + 3];
    }

    // Fixed column for this thread: 2 colchunks of 256 float4 per row.
    const int colchunk = blockIdx.x & 1;
    const int rowgrp   = blockIdx.x >> 1;
    const int col4     = colchunk * 256 + threadIdx.x;   // [0, 512)
    const int dp       = col4 * 2;                       // pair index in row

    // Hoisted weights for pairs dp, dp+1 (L2-resident, loaded once).
    const float4 wa = w4[dp * 2 + 0];  // pair0: k0c0 k0c1 k1c0 k1c1
    const float4 wb = w4[dp * 2 + 1];  // pair0: k2c0 k2c1 k3c0 k3c1
    const float4 wc = w4[dp * 2 + 2];  // pair1
    const float4 wd = w4[dp * 2 + 3];  // pair1

    const int row0 = rowgrp * RPB;
    const long base = (long)row0 * ROW4 + col4;

    // Fully unrolled: all 8 loads issue before computes (compiler-scheduled).
    float4 xv[RPB];
#pragma unroll
    for (int r = 0; r < RPB; ++r)
        xv[r] = x4[base + (long)r * ROW4];

#pragma unroll
    for (int r = 0; r < RPB; ++r) {
        float p0[KCOMP], p1[KCOMP];
#pragma unroll
        for (int k = 0; k < KCOMP; ++k) {
            float d0 = xv[r].x - m0[k];
            float d1 = xv[r].y - m1[k];
            float q  = d0 * (ia[k] * d0 + ib[k] * d1) + d1 * (ic[k] * d0 + idd[k] * d1);
            p0[k] = __expf(-0.5f * q);
            float e0 = xv[r].z - m0[k];
            float e1 = xv[r].w - m1[k];
            float s  = e0 * (ia[k] * e0 + ib[k] * e1) + e1 * (ic[k] * e0 + idd[k] * e1);
            p1[k] = __expf(-0.5f * s);
        }
        float r00 = p0[0] * wa.x + p0[1] * wa.z + p0[2] * wb.x + p0[3] * wb.z;
        float r01 = p0[0] * wa.y + p0[1] * wa.w + p0[2] * wb.y + p0[3] * wb.w;
        float r10 = p1[0] * wc.x + p1[1] * wc.z + p1[2] * wd.x + p1[3] * wd.z;
        float r11 = p1[0] * wc.y + p1[1] * wc.w + p1[2] * wd.y + p1[3] * wd.w;

        float4 ov;
        ov.x = xv[r].x * r00;
        ov.y = xv[r].y * r01;
        ov.z = xv[r].z * r10;
        ov.w = xv[r].w * r11;
        out4[base + (long)r * ROW4] = ov;
    }
}

extern "C" void kernel_launch(void* const* d_in, const int* in_sizes, int n_in,
                              void* d_out, int out_size, void* d_ws, size_t ws_size,
                              hipStream_t stream) {
    const float4* x4    = (const float4*)d_in[0];
    const float*  means = (const float*)d_in[1];
    const float*  icov  = (const float*)d_in[2];
    const float4* w4    = (const float4*)d_in[3];
    float4*       out4  = (float4*)d_out;

    // 2 colchunks * (8192/8) rowgroups = 2048 blocks
    const int grid = 2 * (NROWS / RPB);
    gmm2d_kernel<<<grid, 256, 0, stream>>>(x4, means, icov, w4, out4);
}